// Round 1
// baseline (208.999 us; speedup 1.0000x reference)
//
#include <hip/hip_runtime.h>

// Problem constants: L=2048, B=2, D=1024, H=16 -> hd=64, B*H=32 heads.
// qkv rows r = l*2 + b (4096), head n = b*16 + h.

typedef short  s8v  __attribute__((ext_vector_type(8)));   // 8 x bf16 (bits)
typedef short  s4vv __attribute__((ext_vector_type(4)));
typedef float  f4v  __attribute__((ext_vector_type(4)));
typedef float  f4l  __attribute__((ext_vector_type(4)));

__device__ __forceinline__ short f2bf(float f) {
  union { float f; unsigned u; } x; x.f = f;
  unsigned r = (x.u + 0x7fffu + ((x.u >> 16) & 1u)) >> 16;   // RNE
  return (short)r;
}

#define GLDS16(gp, lp) __builtin_amdgcn_global_load_lds( \
    (const __attribute__((address_space(1))) void*)(gp),  \
    (__attribute__((address_space(3))) void*)(lp), 16, 0, 0)

// ---------------- fp32 -> bf16 cast ----------------
__global__ __launch_bounds__(256) void cast_kernel(const float* __restrict__ in,
                                                   short* __restrict__ out, int n4) {
  int i = blockIdx.x * 256 + threadIdx.x;
  if (i < n4) {
    f4l v = ((const f4l*)in)[i];
    s4vv o;
    o[0] = f2bf(v[0]); o[1] = f2bf(v[1]); o[2] = f2bf(v[2]); o[3] = f2bf(v[3]);
    ((s4vv*)out)[i] = o;
  }
}

// ---------------- GEMM core: C[128x128] = A[128xK] * B[128xK]^T ----------------
// BK=64 (128B LDS rows, 8 slots), slot-swizzle s' = s ^ (row&7), staged via
// global_load_lds (linear dest, pre-swizzled global source).

// GEMM1: qkv = x @ W_in^T + b_in; scatter to Q/K/V head layout [32][2048][64] bf16, q*=0.125
__global__ __launch_bounds__(256) void gemm_qkv(const short* __restrict__ A,
                                                const short* __restrict__ B,
                                                const float* __restrict__ bin,
                                                short* __restrict__ Qh,
                                                short* __restrict__ Kh,
                                                short* __restrict__ Vh) {
  __shared__ __align__(16) short As[128 * 64];
  __shared__ __align__(16) short Bs[128 * 64];
  const int tid = threadIdx.x;
  const int w = tid >> 6, lane = tid & 63;
  const int g = lane >> 4, c15 = lane & 15;
  const int wr = w >> 1, wc = w & 1;
  const int rowbase = blockIdx.y << 7;
  const int colbase = blockIdx.x << 7;
  const int rl = lane >> 3, sp = lane & 7;
  const int swz = (sp ^ rl) << 3;           // element offset of swizzled 16B slot

  f4v acc[4][4] = {};

  for (int kt = 0; kt < 16; ++kt) {
#pragma unroll
    for (int c2 = 0; c2 < 4; ++c2) {
      const int chunk = (w << 2) + c2;      // 0..15, 8 rows each
      const int row = (chunk << 3) + rl;
      GLDS16(A + ((size_t)(rowbase + row) << 10) + (kt << 6) + swz, &As[chunk << 9]);
      GLDS16(B + ((size_t)(colbase + row) << 10) + (kt << 6) + swz, &Bs[chunk << 9]);
    }
    __syncthreads();
#pragma unroll
    for (int kk = 0; kk < 2; ++kk) {
      s8v af[4], bf[4];
#pragma unroll
      for (int m = 0; m < 4; ++m) {
        const int row = (wr << 6) + (m << 4) + c15;
        af[m] = *(const s8v*)((const char*)As + row * 128 + ((((kk << 2) | g) ^ (row & 7)) << 4));
        const int col = (wc << 6) + (m << 4) + c15;
        bf[m] = *(const s8v*)((const char*)Bs + col * 128 + ((((kk << 2) | g) ^ (col & 7)) << 4));
      }
#pragma unroll
      for (int m = 0; m < 4; ++m)
#pragma unroll
        for (int n = 0; n < 4; ++n)
          acc[m][n] = __builtin_amdgcn_mfma_f32_16x16x32_bf16(af[m], bf[n], acc[m][n], 0, 0, 0);
    }
    __syncthreads();
  }

  const int r0 = rowbase + (wr << 6) + (g << 2);
  const int c0 = colbase + (wc << 6) + c15;
#pragma unroll
  for (int n = 0; n < 4; ++n) {
    const int col = c0 + (n << 4);
    const int which = col >> 10;
    const int dd = col & 1023;
    const int hh = dd >> 6, ee = dd & 63;
    const float bias = bin[col];
    short* dst = (which == 0) ? Qh : ((which == 1) ? Kh : Vh);
    const float mul = (which == 0) ? 0.125f : 1.0f;   // 1/sqrt(64)
#pragma unroll
    for (int m = 0; m < 4; ++m) {
#pragma unroll
      for (int j = 0; j < 4; ++j) {
        const int row = r0 + (m << 4) + j;
        const int li = row >> 1, bb = row & 1;
        const int nh = (bb << 4) + hh;
        dst[(((size_t)nh * 2048 + li) << 6) + ee] = f2bf((acc[m][n][j] + bias) * mul);
      }
    }
  }
}

// GEMM2: out = z @ W_out^T + b_out (fp32 out)
__global__ __launch_bounds__(256) void gemm_out(const short* __restrict__ A,
                                                const short* __restrict__ B,
                                                const float* __restrict__ bout,
                                                float* __restrict__ out) {
  __shared__ __align__(16) short As[128 * 64];
  __shared__ __align__(16) short Bs[128 * 64];
  const int tid = threadIdx.x;
  const int w = tid >> 6, lane = tid & 63;
  const int g = lane >> 4, c15 = lane & 15;
  const int wr = w >> 1, wc = w & 1;
  const int rowbase = blockIdx.y << 7;
  const int colbase = blockIdx.x << 7;
  const int rl = lane >> 3, sp = lane & 7;
  const int swz = (sp ^ rl) << 3;

  f4v acc[4][4] = {};

  for (int kt = 0; kt < 16; ++kt) {
#pragma unroll
    for (int c2 = 0; c2 < 4; ++c2) {
      const int chunk = (w << 2) + c2;
      const int row = (chunk << 3) + rl;
      GLDS16(A + ((size_t)(rowbase + row) << 10) + (kt << 6) + swz, &As[chunk << 9]);
      GLDS16(B + ((size_t)(colbase + row) << 10) + (kt << 6) + swz, &Bs[chunk << 9]);
    }
    __syncthreads();
#pragma unroll
    for (int kk = 0; kk < 2; ++kk) {
      s8v af[4], bf[4];
#pragma unroll
      for (int m = 0; m < 4; ++m) {
        const int row = (wr << 6) + (m << 4) + c15;
        af[m] = *(const s8v*)((const char*)As + row * 128 + ((((kk << 2) | g) ^ (row & 7)) << 4));
        const int col = (wc << 6) + (m << 4) + c15;
        bf[m] = *(const s8v*)((const char*)Bs + col * 128 + ((((kk << 2) | g) ^ (col & 7)) << 4));
      }
#pragma unroll
      for (int m = 0; m < 4; ++m)
#pragma unroll
        for (int n = 0; n < 4; ++n)
          acc[m][n] = __builtin_amdgcn_mfma_f32_16x16x32_bf16(af[m], bf[n], acc[m][n], 0, 0, 0);
    }
    __syncthreads();
  }

  const int r0 = rowbase + (wr << 6) + (g << 2);
  const int c0 = colbase + (wc << 6) + c15;
#pragma unroll
  for (int n = 0; n < 4; ++n) {
    const int col = c0 + (n << 4);
    const float bias = bout[col];
#pragma unroll
    for (int m = 0; m < 4; ++m) {
#pragma unroll
      for (int j = 0; j < 4; ++j) {
        const int row = r0 + (m << 4) + j;
        out[((size_t)row << 10) + col] = acc[m][n][j] + bias;
      }
    }
  }
}

// ---------------- flash attention ----------------
// grid (32 qtiles, 32 heads), 4 waves/block, 16 q-rows/wave, KV tile = 64.
__global__ __launch_bounds__(256) void attn(const short* __restrict__ Qh,
                                            const short* __restrict__ Kh,
                                            const short* __restrict__ Vh,
                                            const float* __restrict__ mask,
                                            short* __restrict__ Z) {
  __shared__ __align__(16) short Ks[64 * 64];     // [kcol][e], swizzled 16B slots
  __shared__ __align__(16) short VT[64 * 72];     // [e][k], pad 72 (bank-clean)
  __shared__ __align__(16) short Ps[4][16 * 64];  // per-wave P tile, swizzled slots
  const int tid = threadIdx.x;
  const int w = tid >> 6, lane = tid & 63;
  const int g = lane >> 4, c15 = lane & 15;
  const int n = blockIdx.y, qt = blockIdx.x;
  const int rl = lane >> 3, sp = lane & 7;
  const int swz = (sp ^ rl) << 3;

  // Q fragments held in registers for the whole kernel (A-operand layout)
  const short* Qp = Qh + (((size_t)n * 2048 + (qt << 6) + (w << 4)) << 6);
  s8v aq[2];
#pragma unroll
  for (int kk = 0; kk < 2; ++kk)
    aq[kk] = *(const s8v*)(Qp + (c15 << 6) + (kk << 5) + (g << 3));

  const short* Kbase = Kh + ((size_t)n << 17);
  const short* Vbase = Vh + ((size_t)n << 17);

  f4v accv[4] = {};
  float mrow[4], lrow[4];
#pragma unroll
  for (int j = 0; j < 4; ++j) { mrow[j] = -1e30f; lrow[j] = 0.0f; }

  for (int kt = 0; kt < 32; ++kt) {
    // stage K tile via global_load_lds (swizzled source, linear dest)
#pragma unroll
    for (int c2 = 0; c2 < 2; ++c2) {
      const int chunk = (w << 1) + c2;            // 0..7 (8 rows each)
      const int kr = (chunk << 3) + rl;
      GLDS16(Kbase + (((size_t)(kt << 6) + kr) << 6) + swz, &Ks[chunk << 9]);
    }
    // stage V transposed: lane = k-row, wave covers 16 e-columns
    {
      const short* vp = Vbase + (((size_t)(kt << 6) + lane) << 6) + (w << 4);
      s8v v0 = *(const s8v*)(vp);
      s8v v1 = *(const s8v*)(vp + 8);
#pragma unroll
      for (int i = 0; i < 8; ++i) VT[((w << 4) + i) * 72 + lane] = v0[i];
#pragma unroll
      for (int i = 0; i < 8; ++i) VT[((w << 4) + 8 + i) * 72 + lane] = v1[i];
    }
    __syncthreads();

    // S = Q K^T  (16q x 64k per wave)
    f4v s4[4] = {};
#pragma unroll
    for (int kk = 0; kk < 2; ++kk) {
      s8v bk[4];
#pragma unroll
      for (int f = 0; f < 4; ++f) {
        const int col = (f << 4) + c15;
        bk[f] = *(const s8v*)((const char*)Ks + col * 128 + ((((kk << 2) | g) ^ (col & 7)) << 4));
      }
#pragma unroll
      for (int f = 0; f < 4; ++f)
        s4[f] = __builtin_amdgcn_mfma_f32_16x16x32_bf16(aq[kk], bk[f], s4[f], 0, 0, 0);
    }
    // + mask (broadcast over heads)
    const size_t mrb = ((size_t)((qt << 6) + (w << 4) + (g << 2))) * 2048 + (kt << 6) + c15;
#pragma unroll
    for (int f = 0; f < 4; ++f)
#pragma unroll
      for (int j = 0; j < 4; ++j)
        s4[f][j] += mask[mrb + (size_t)j * 2048 + (f << 4)];

    // online softmax (rows live on (g,j); cols on lane&15 -> 4-step shfl reduce)
    float tmax[4];
#pragma unroll
    for (int j = 0; j < 4; ++j)
      tmax[j] = fmaxf(fmaxf(s4[0][j], s4[1][j]), fmaxf(s4[2][j], s4[3][j]));
#pragma unroll
    for (int st = 1; st < 16; st <<= 1)
#pragma unroll
      for (int j = 0; j < 4; ++j)
        tmax[j] = fmaxf(tmax[j], __shfl_xor(tmax[j], st));
    float scale[4];
#pragma unroll
    for (int j = 0; j < 4; ++j) {
      const float mnew = fmaxf(mrow[j], tmax[j]);
      scale[j] = __expf(mrow[j] - mnew);
      mrow[j] = mnew;
    }
    float rs[4] = {0.f, 0.f, 0.f, 0.f};
#pragma unroll
    for (int f = 0; f < 4; ++f)
#pragma unroll
      for (int j = 0; j < 4; ++j) {
        const float p = __expf(s4[f][j] - mrow[j]);
        s4[f][j] = p;
        rs[j] += p;
      }
#pragma unroll
    for (int st = 1; st < 16; st <<= 1)
#pragma unroll
      for (int j = 0; j < 4; ++j)
        rs[j] += __shfl_xor(rs[j], st);
#pragma unroll
    for (int j = 0; j < 4; ++j)
      lrow[j] = lrow[j] * scale[j] + rs[j];
#pragma unroll
    for (int ef = 0; ef < 4; ++ef)
#pragma unroll
      for (int j = 0; j < 4; ++j)
        accv[ef][j] *= scale[j];

    // P -> LDS (bf16, swizzled slots), per-wave buffer (no barrier needed)
    short* Pw = &Ps[w][0];
#pragma unroll
    for (int f = 0; f < 4; ++f) {
      const int slot_in = (f << 1) + (c15 >> 3);
#pragma unroll
      for (int j = 0; j < 4; ++j) {
        const int row = (g << 2) + j;
        *(short*)((char*)Pw + row * 128 + ((slot_in ^ (row & 7)) << 4) + ((c15 & 7) << 1)) =
            f2bf(s4[f][j]);
      }
    }
    // PV: acc += P @ V
#pragma unroll
    for (int kk = 0; kk < 2; ++kk) {
      s8v pa;
      __builtin_memcpy(&pa, (const char*)Pw + c15 * 128 + ((((kk << 2) | g) ^ (c15 & 7)) << 4), 16);
#pragma unroll
      for (int ef = 0; ef < 4; ++ef) {
        s8v bv = *(const s8v*)((const char*)VT + (((ef << 4) + c15) * 144) + (kk << 6) + (g << 4));
        accv[ef] = __builtin_amdgcn_mfma_f32_16x16x32_bf16(pa, bv, accv[ef], 0, 0, 0);
      }
    }
    __syncthreads();
  }

  // epilogue: z / l, write bf16 in (r = l*2+b, d = h*64+e) layout for GEMM2
  float inv[4];
#pragma unroll
  for (int j = 0; j < 4; ++j) inv[j] = 1.0f / lrow[j];
  const int li0 = (qt << 6) + (w << 4) + (g << 2);
  const int bb = n >> 4, hh = n & 15;
#pragma unroll
  for (int ef = 0; ef < 4; ++ef) {
    const int d = (hh << 6) + (ef << 4) + c15;
#pragma unroll
    for (int j = 0; j < 4; ++j) {
      const size_t r = ((size_t)(li0 + j) << 1) + bb;
      Z[(r << 10) + d] = f2bf(accv[ef][j] * inv[j]);
    }
  }
}

extern "C" void kernel_launch(void* const* d_in, const int* in_sizes, int n_in,
                              void* d_out, int out_size, void* d_ws, size_t ws_size,
                              hipStream_t stream) {
  const float* xq   = (const float*)d_in[0];   // q == k == v
  const float* mask = (const float*)d_in[3];
  const float* Win  = (const float*)d_in[4];
  const float* bin  = (const float*)d_in[5];
  const float* Wout = (const float*)d_in[6];
  const float* bout = (const float*)d_in[7];
  float* out = (float*)d_out;

  char* ws = (char*)d_ws;
  short* xb  = (short*)(ws);                      // [4096][1024] bf16, 8 MB
  short* wib = (short*)(ws + (8ull  << 20));      // [3072][1024] bf16, 6 MB
  short* wob = (short*)(ws + (14ull << 20));      // [1024][1024] bf16, 2 MB
  short* Qh  = (short*)(ws + (16ull << 20));      // [32][2048][64] bf16, 8 MB
  short* Kh  = (short*)(ws + (24ull << 20));
  short* Vh  = (short*)(ws + (32ull << 20));
  short* Zb  = (short*)(ws + (40ull << 20));      // [4096][1024] bf16, 8 MB

  cast_kernel<<<4096, 256, 0, stream>>>(xq,  xb,  4096 * 1024 / 4);
  cast_kernel<<<3072, 256, 0, stream>>>(Win, wib, 3072 * 1024 / 4);
  cast_kernel<<<1024, 256, 0, stream>>>(Wout, wob, 1024 * 1024 / 4);
  gemm_qkv<<<dim3(24, 32), 256, 0, stream>>>(xb, wib, bin, Qh, Kh, Vh);
  attn<<<dim3(32, 32), 256, 0, stream>>>(Qh, Kh, Vh, mask, Zb);
  gemm_out<<<dim3(8, 32), 256, 0, stream>>>(Zb, wob, bout, out);
}